// Round 1
// baseline (7800.899 us; speedup 1.0000x reference)
//
#include <hip/hip_runtime.h>

#define NN 50000
#define NE 800000
#define CC 128
#define SLAB (NN * CC)
#define BN_EPS 1e-5f

// ---------------- utility ----------------
__global__ void zero_int_kernel(int* __restrict__ p, int n) {
  int i = blockIdx.x * blockDim.x + threadIdx.x;
  if (i < n) p[i] = 0;
}

// ---------------- CSR build ----------------
__global__ void count_kernel(const int* __restrict__ dst, int* __restrict__ counts) {
  int e = blockIdx.x * blockDim.x + threadIdx.x;
  if (e < NE) atomicAdd(&counts[dst[e]], 1);
}

__global__ void scan1_kernel(const int* __restrict__ counts, int* __restrict__ excl,
                             int* __restrict__ blocksum) {
  __shared__ int s[256];
  int t = threadIdx.x;
  int i = blockIdx.x * 256 + t;
  int v = (i < NN) ? counts[i] : 0;
  s[t] = v;
  for (int off = 1; off < 256; off <<= 1) {
    __syncthreads();
    int add = (t >= off) ? s[t - off] : 0;
    __syncthreads();
    s[t] += add;
  }
  __syncthreads();
  if (i < NN) excl[i] = s[t] - v;            // exclusive within block
  if (t == 255) blocksum[blockIdx.x] = s[255];
}

__global__ void scan2_kernel(int* __restrict__ blocksum, int nb) {
  __shared__ int s[256];
  int t = threadIdx.x;
  int v = (t < nb) ? blocksum[t] : 0;
  s[t] = v;
  for (int off = 1; off < 256; off <<= 1) {
    __syncthreads();
    int add = (t >= off) ? s[t - off] : 0;
    __syncthreads();
    s[t] += add;
  }
  __syncthreads();
  if (t < nb) blocksum[t] = s[t] - v;        // exclusive
}

__global__ void scan3_kernel(int* __restrict__ excl, const int* __restrict__ blocksum) {
  int i = blockIdx.x * 256 + threadIdx.x;
  if (i < NN) excl[i] += blocksum[blockIdx.x];
}

__global__ void fill_kernel(const int* __restrict__ src, const int* __restrict__ dst,
                            const int* __restrict__ starts, int* __restrict__ fill,
                            int* __restrict__ bucket) {
  int e = blockIdx.x * blockDim.x + threadIdx.x;
  if (e < NE) {
    int d = dst[e];
    int pos = atomicAdd(&fill[d], 1);
    bucket[starts[d] + pos] = src[e];
  }
}

// ---------------- gather: agg = h + sum_{j->i} h[j] ----------------
// one wave (64 lanes) per node, float2 per lane covers 128 channels
__global__ void gather_kernel(const float* __restrict__ h, const int* __restrict__ starts,
                              const int* __restrict__ counts, const int* __restrict__ bucket,
                              float* __restrict__ agg) {
  int node = blockIdx.x * 4 + (threadIdx.x >> 6);
  int lane = threadIdx.x & 63;
  const float2* h2 = (const float2*)h;
  float2 acc = h2[node * 64 + lane];         // (1+eps)*x with eps=0
  int s = starts[node];
  int n = counts[node];
  for (int i = 0; i < n; ++i) {
    int sr = bucket[s + i];
    float2 v = h2[sr * 64 + lane];
    acc.x += v.x;
    acc.y += v.y;
  }
  ((float2*)agg)[node * 64 + lane] = acc;
}

// ---------------- GEMM: out = op(A) @ W + bias, optional column stats ----------------
// op(A) = relu(bn_a[k]*A + bn_d[k]) per input channel k when FUSE_BN.
// Tile: 64 rows x 128 cols, 128 threads, 8x8 acc per thread, K chunked by 32.
template <bool FUSE_BN, bool STATS>
__global__ __launch_bounds__(128) void gemm_kernel(
    const float* __restrict__ A, const float* __restrict__ W, const float* __restrict__ bias,
    float* __restrict__ out, const float* __restrict__ bn_a, const float* __restrict__ bn_d,
    float* __restrict__ stats) {
  __shared__ float As[32][64];    // [k][row]
  __shared__ float Ws[32][128];   // [k][col], column-XOR swizzled
  const int t = threadIdx.x;
  const int tr = t >> 4;          // 0..7  -> rows tr*8..tr*8+7
  const int tc = t & 15;          // 0..15 -> cols tc*8..tc*8+7
  const int rowbase = blockIdx.x * 64;

  float acc[8][8];
#pragma unroll
  for (int i = 0; i < 8; ++i)
#pragma unroll
    for (int j = 0; j < 8; ++j) acc[i][j] = 0.f;

  for (int kc = 0; kc < CC; kc += 32) {
    // stage A chunk (transposed to [k][row])
#pragma unroll
    for (int i = 0; i < 4; ++i) {
      int gr = i * 16 + (t >> 3);          // 0..63
      int kk = (t & 7) * 4;                // 0,4,...,28
      int r = rowbase + gr;
      float4 v = make_float4(0.f, 0.f, 0.f, 0.f);
      if (r < NN) v = *(const float4*)&A[r * CC + kc + kk];
      if (FUSE_BN) {
        int k0 = kc + kk;
        v.x = fmaxf(fmaf(v.x, bn_a[k0 + 0], bn_d[k0 + 0]), 0.f);
        v.y = fmaxf(fmaf(v.y, bn_a[k0 + 1], bn_d[k0 + 1]), 0.f);
        v.z = fmaxf(fmaf(v.z, bn_a[k0 + 2], bn_d[k0 + 2]), 0.f);
        v.w = fmaxf(fmaf(v.w, bn_a[k0 + 3], bn_d[k0 + 3]), 0.f);
      }
      As[kk + 0][gr] = v.x;
      As[kk + 1][gr] = v.y;
      As[kk + 2][gr] = v.z;
      As[kk + 3][gr] = v.w;
    }
    // stage W chunk (swizzled: logical col c stored at c ^ ((c>>5)<<3))
#pragma unroll
    for (int i = 0; i < 8; ++i) {
      int k = i * 4 + (t >> 5);            // 0..31
      int c = (t & 31) * 4;                // 0..124
      float4 v = *(const float4*)&W[(kc + k) * CC + c];
      int p = c ^ (((c >> 5) & 3) << 3);
      *(float4*)&Ws[k][p] = v;
    }
    __syncthreads();
#pragma unroll
    for (int k = 0; k < 32; ++k) {
      const float4 a0 = *(const float4*)&As[k][tr * 8];
      const float4 a1 = *(const float4*)&As[k][tr * 8 + 4];
      int c0 = tc * 8;
      int p0 = c0 ^ (((c0 >> 5) & 3) << 3);
      const float4 w0 = *(const float4*)&Ws[k][p0];
      const float4 w1 = *(const float4*)&Ws[k][p0 + 4];
      float a[8] = {a0.x, a0.y, a0.z, a0.w, a1.x, a1.y, a1.z, a1.w};
      float w[8] = {w0.x, w0.y, w0.z, w0.w, w1.x, w1.y, w1.z, w1.w};
#pragma unroll
      for (int i = 0; i < 8; ++i)
#pragma unroll
        for (int j = 0; j < 8; ++j) acc[i][j] = fmaf(a[i], w[j], acc[i][j]);
    }
    __syncthreads();
  }

  // epilogue: bias add, store, column stats
  int c0 = tc * 8;
  float4 bv0 = *(const float4*)&bias[c0];
  float4 bv1 = *(const float4*)&bias[c0 + 4];
  float bcol[8] = {bv0.x, bv0.y, bv0.z, bv0.w, bv1.x, bv1.y, bv1.z, bv1.w};
  float colsum[8], colsq[8];
#pragma unroll
  for (int j = 0; j < 8; ++j) {
    colsum[j] = 0.f;
    colsq[j] = 0.f;
  }
#pragma unroll
  for (int i = 0; i < 8; ++i) {
    int r = rowbase + tr * 8 + i;
    if (r < NN) {
      float vals[8];
#pragma unroll
      for (int j = 0; j < 8; ++j) vals[j] = acc[i][j] + bcol[j];
      float4 o0 = make_float4(vals[0], vals[1], vals[2], vals[3]);
      float4 o1 = make_float4(vals[4], vals[5], vals[6], vals[7]);
      *(float4*)&out[r * CC + c0] = o0;
      *(float4*)&out[r * CC + c0 + 4] = o1;
      if (STATS) {
#pragma unroll
        for (int j = 0; j < 8; ++j) {
          colsum[j] += vals[j];
          colsq[j] += vals[j] * vals[j];
        }
      }
    }
  }
  if (STATS) {
#pragma unroll
    for (int j = 0; j < 8; ++j) {
      atomicAdd(&stats[c0 + j], colsum[j]);
      atomicAdd(&stats[CC + c0 + j], colsq[j]);
    }
  }
}

// ---------------- BN finalize: a = g*rsqrt(var+eps), d = beta - mu*a ----------------
__global__ void finalize_kernel(const float* __restrict__ stats, const float* __restrict__ g,
                                const float* __restrict__ be, float* __restrict__ bn_a,
                                float* __restrict__ bn_d) {
  int c = threadIdx.x;
  float mu = stats[c] * (1.0f / NN);
  float var = stats[CC + c] * (1.0f / NN) - mu * mu;
  var = fmaxf(var, 0.f);
  float inv = rsqrtf(var + BN_EPS);
  float a = g[c] * inv;
  bn_a[c] = a;
  bn_d[c] = fmaf(-mu, a, be[c]);
}

// ---------------- BN2 + relu apply -> output slab ----------------
__global__ void apply_kernel(const float* __restrict__ tmp, const float* __restrict__ bn_a,
                             const float* __restrict__ bn_d, float* __restrict__ outslab) {
  int i = blockIdx.x * blockDim.x + threadIdx.x;  // indexes float4, SLAB/4 total
  float4 v = ((const float4*)tmp)[i];
  int c = (i & 31) << 2;
  float4 a = *(const float4*)&bn_a[c];
  float4 d = *(const float4*)&bn_d[c];
  v.x = fmaxf(fmaf(v.x, a.x, d.x), 0.f);
  v.y = fmaxf(fmaf(v.y, a.y, d.y), 0.f);
  v.z = fmaxf(fmaf(v.z, a.z, d.z), 0.f);
  v.w = fmaxf(fmaf(v.w, a.w, d.w), 0.f);
  ((float4*)outslab)[i] = v;
}

// ---------------- launch ----------------
extern "C" void kernel_launch(void* const* d_in, const int* in_sizes, int n_in,
                              void* d_out, int out_size, void* d_ws, size_t ws_size,
                              hipStream_t stream) {
  const float* x    = (const float*)d_in[0];
  const int*   edge = (const int*)d_in[1];
  // d_in[2] = batch: structurally node i -> graph i/1000 -> to_dense_batch == reshape
  const float* fh_W = (const float*)d_in[3];
  const float* fh_b = (const float*)d_in[4];
  const float* W1   = (const float*)d_in[5];
  const float* b1   = (const float*)d_in[6];
  const float* g1   = (const float*)d_in[7];
  const float* be1  = (const float*)d_in[8];
  const float* W2   = (const float*)d_in[9];
  const float* b2   = (const float*)d_in[10];
  const float* g2   = (const float*)d_in[11];
  const float* be2  = (const float*)d_in[12];
  float* out = (float*)d_out;

  const int* src = edge;
  const int* dst = edge + NE;

  // workspace layout (all 16B aligned)
  int* counts   = (int*)d_ws;        // 50048
  int* fill     = counts + 50048;    // 50048
  int* starts   = fill + 50048;      // 50048
  int* blocksum = starts + 50048;    // 256
  int* bucket   = blocksum + 256;    // 800000
  float* stats  = (float*)(bucket + NE);  // 512 (two BN stat sets)
  float* bn_a1  = stats + 512;
  float* bn_d1  = bn_a1 + CC;
  float* bn_a2  = bn_d1 + CC;
  float* bn_d2  = bn_a2 + CC;
  float* aggbuf = stats + 1024;      // SLAB floats (also reused as tmp2)
  float* tmp1   = aggbuf + SLAB;     // SLAB floats

  // CSR build (counts and fill are contiguous -> one zero pass)
  zero_int_kernel<<<(100096 + 255) / 256, 256, 0, stream>>>(counts, 100096);
  count_kernel<<<NE / 256, 256, 0, stream>>>(dst, counts);
  scan1_kernel<<<196, 256, 0, stream>>>(counts, starts, blocksum);
  scan2_kernel<<<1, 256, 0, stream>>>(blocksum, 196);
  scan3_kernel<<<196, 256, 0, stream>>>(starts, blocksum);
  fill_kernel<<<NE / 256, 256, 0, stream>>>(src, dst, starts, fill, bucket);

  // first head: out slab 0 = x @ fh_W + fh_b
  gemm_kernel<false, false><<<782, 128, 0, stream>>>(x, fh_W, fh_b, out, nullptr, nullptr, nullptr);

  for (int l = 0; l < 3; ++l) {
    const float* h = out + l * SLAB;
    zero_int_kernel<<<2, 256, 0, stream>>>((int*)stats, 512);
    gather_kernel<<<NN / 4, 256, 0, stream>>>(h, starts, counts, bucket, aggbuf);
    gemm_kernel<false, true><<<782, 128, 0, stream>>>(aggbuf, W1 + l * CC * CC, b1 + l * CC,
                                                      tmp1, nullptr, nullptr, stats);
    finalize_kernel<<<1, 128, 0, stream>>>(stats, g1 + l * CC, be1 + l * CC, bn_a1, bn_d1);
    gemm_kernel<true, true><<<782, 128, 0, stream>>>(tmp1, W2 + l * CC * CC, b2 + l * CC,
                                                     aggbuf, bn_a1, bn_d1, stats + 256);
    finalize_kernel<<<1, 128, 0, stream>>>(stats + 256, g2 + l * CC, be2 + l * CC, bn_a2, bn_d2);
    apply_kernel<<<SLAB / 4 / 256, 256, 0, stream>>>(aggbuf, bn_a2, bn_d2, out + (l + 1) * SLAB);
  }
}

// Round 2
// 4211.549 us; speedup vs baseline: 1.8523x; 1.8523x over previous
//
#include <hip/hip_runtime.h>

#define NN 50000
#define NE 800000
#define CC 128
#define SLAB (NN * CC)
#define BN_EPS 1e-5f

// ---------------- utility ----------------
__global__ void zero_int_kernel(int* __restrict__ p, int n) {
  int i = blockIdx.x * blockDim.x + threadIdx.x;
  if (i < n) p[i] = 0;
}

// ---------------- CSR build ----------------
__global__ void count_kernel(const int* __restrict__ dst, int* __restrict__ counts) {
  int e = blockIdx.x * blockDim.x + threadIdx.x;
  if (e < NE) atomicAdd(&counts[dst[e]], 1);
}

__global__ void scan1_kernel(const int* __restrict__ counts, int* __restrict__ excl,
                             int* __restrict__ blocksum) {
  __shared__ int s[256];
  int t = threadIdx.x;
  int i = blockIdx.x * 256 + t;
  int v = (i < NN) ? counts[i] : 0;
  s[t] = v;
  for (int off = 1; off < 256; off <<= 1) {
    __syncthreads();
    int add = (t >= off) ? s[t - off] : 0;
    __syncthreads();
    s[t] += add;
  }
  __syncthreads();
  if (i < NN) excl[i] = s[t] - v;            // exclusive within block
  if (t == 255) blocksum[blockIdx.x] = s[255];
}

__global__ void scan2_kernel(int* __restrict__ blocksum, int nb) {
  __shared__ int s[256];
  int t = threadIdx.x;
  int v = (t < nb) ? blocksum[t] : 0;
  s[t] = v;
  for (int off = 1; off < 256; off <<= 1) {
    __syncthreads();
    int add = (t >= off) ? s[t - off] : 0;
    __syncthreads();
    s[t] += add;
  }
  __syncthreads();
  if (t < nb) blocksum[t] = s[t] - v;        // exclusive
}

__global__ void scan3_kernel(int* __restrict__ excl, const int* __restrict__ blocksum) {
  int i = blockIdx.x * 256 + threadIdx.x;
  if (i < NN) excl[i] += blocksum[blockIdx.x];
}

__global__ void fill_kernel(const int* __restrict__ src, const int* __restrict__ dst,
                            const int* __restrict__ starts, int* __restrict__ fill,
                            int* __restrict__ bucket) {
  int e = blockIdx.x * blockDim.x + threadIdx.x;
  if (e < NE) {
    int d = dst[e];
    int pos = atomicAdd(&fill[d], 1);
    bucket[starts[d] + pos] = src[e];
  }
}

// ---------------- gather: agg = h + sum_{j->i} h[j] ----------------
// one wave (64 lanes) per node, float2 per lane covers 128 channels
__global__ void gather_kernel(const float* __restrict__ h, const int* __restrict__ starts,
                              const int* __restrict__ counts, const int* __restrict__ bucket,
                              float* __restrict__ agg) {
  int node = blockIdx.x * 4 + (threadIdx.x >> 6);
  int lane = threadIdx.x & 63;
  const float2* h2 = (const float2*)h;
  float2 acc = h2[node * 64 + lane];         // (1+eps)*x with eps=0
  int s = starts[node];
  int n = counts[node];
  for (int i = 0; i < n; ++i) {
    int sr = bucket[s + i];
    float2 v = h2[sr * 64 + lane];
    acc.x += v.x;
    acc.y += v.y;
  }
  ((float2*)agg)[node * 64 + lane] = acc;
}

// ---------------- GEMM: out = op(A) @ W + bias, optional column stats ----------------
// op(A) = relu(bn_a[k]*A + bn_d[k]) per input channel k when FUSE_BN.
// Block: 256 threads (4 waves). Tile 64 rows x 128 cols. Thread: 8 rows x 4 cols.
// A staged row-major (no transpose), read as float4 along K. BK=32, 4 chunks.
template <bool FUSE_BN, bool STATS>
__global__ __launch_bounds__(256) void gemm_kernel(
    const float* __restrict__ A, const float* __restrict__ W, const float* __restrict__ bias,
    float* __restrict__ out, const float* __restrict__ bn_a, const float* __restrict__ bn_d,
    float* __restrict__ stats) {
  __shared__ float As[64][36];    // [row][k], padded 32->36 (staging writes 2-way max)
  __shared__ float Ws[32][128];   // [k][col]
  const int t = threadIdx.x;
  const int tc = t & 31;          // col group: cols tc*4..tc*4+3
  const int tr = t >> 5;          // row group: rows tr*8..tr*8+7
  const int rowbase = blockIdx.x * 64;

  float4 acc[8];
#pragma unroll
  for (int i = 0; i < 8; ++i) acc[i] = make_float4(0.f, 0.f, 0.f, 0.f);

  // staging index precompute
  const int sa_r = t >> 3;         // 0..31
  const int sa_k = (t & 7) * 4;    // 0,4,...,28
  const int sw_k = t >> 5;         // 0..7
  const int sw_c = (t & 31) * 4;   // 0..124

  for (int kc = 0; kc < CC; kc += 32) {
    // stage A chunk: 64 rows x 32 k, row-major, float4 loads+stores
#pragma unroll
    for (int i = 0; i < 2; ++i) {
      int r = i * 32 + sa_r;
      int rg = rowbase + r;
      float4 v = make_float4(0.f, 0.f, 0.f, 0.f);
      if (rg < NN) v = *(const float4*)&A[rg * CC + kc + sa_k];
      if (FUSE_BN) {
        int k0 = kc + sa_k;
        v.x = fmaxf(fmaf(v.x, bn_a[k0 + 0], bn_d[k0 + 0]), 0.f);
        v.y = fmaxf(fmaf(v.y, bn_a[k0 + 1], bn_d[k0 + 1]), 0.f);
        v.z = fmaxf(fmaf(v.z, bn_a[k0 + 2], bn_d[k0 + 2]), 0.f);
        v.w = fmaxf(fmaf(v.w, bn_a[k0 + 3], bn_d[k0 + 3]), 0.f);
      }
      *(float4*)&As[r][sa_k] = v;
    }
    // stage W chunk: 32 k x 128 cols
#pragma unroll
    for (int j = 0; j < 4; ++j) {
      int k = j * 8 + sw_k;
      float4 v = *(const float4*)&W[(kc + k) * CC + sw_c];
      *(float4*)&Ws[k][sw_c] = v;
    }
    __syncthreads();

    // inner: 8 sub-steps of 4 k's
#pragma unroll
    for (int kb = 0; kb < 8; ++kb) {
      float4 w0 = *(const float4*)&Ws[kb * 4 + 0][tc * 4];
      float4 w1 = *(const float4*)&Ws[kb * 4 + 1][tc * 4];
      float4 w2 = *(const float4*)&Ws[kb * 4 + 2][tc * 4];
      float4 w3 = *(const float4*)&Ws[kb * 4 + 3][tc * 4];
#pragma unroll
      for (int i = 0; i < 8; ++i) {
        float4 a = *(const float4*)&As[tr * 8 + i][kb * 4];
        acc[i].x = fmaf(a.x, w0.x, acc[i].x);
        acc[i].y = fmaf(a.x, w0.y, acc[i].y);
        acc[i].z = fmaf(a.x, w0.z, acc[i].z);
        acc[i].w = fmaf(a.x, w0.w, acc[i].w);
        acc[i].x = fmaf(a.y, w1.x, acc[i].x);
        acc[i].y = fmaf(a.y, w1.y, acc[i].y);
        acc[i].z = fmaf(a.y, w1.z, acc[i].z);
        acc[i].w = fmaf(a.y, w1.w, acc[i].w);
        acc[i].x = fmaf(a.z, w2.x, acc[i].x);
        acc[i].y = fmaf(a.z, w2.y, acc[i].y);
        acc[i].z = fmaf(a.z, w2.z, acc[i].z);
        acc[i].w = fmaf(a.z, w2.w, acc[i].w);
        acc[i].x = fmaf(a.w, w3.x, acc[i].x);
        acc[i].y = fmaf(a.w, w3.y, acc[i].y);
        acc[i].z = fmaf(a.w, w3.z, acc[i].z);
        acc[i].w = fmaf(a.w, w3.w, acc[i].w);
      }
    }
    __syncthreads();
  }

  // epilogue: bias add, store, column stats
  const int c0 = tc * 4;
  float4 bv = *(const float4*)&bias[c0];
  float4 csum = make_float4(0.f, 0.f, 0.f, 0.f);
  float4 csq = make_float4(0.f, 0.f, 0.f, 0.f);
#pragma unroll
  for (int i = 0; i < 8; ++i) {
    int r = rowbase + tr * 8 + i;
    if (r < NN) {
      float4 v;
      v.x = acc[i].x + bv.x;
      v.y = acc[i].y + bv.y;
      v.z = acc[i].z + bv.z;
      v.w = acc[i].w + bv.w;
      *(float4*)&out[r * CC + c0] = v;
      if (STATS) {
        csum.x += v.x; csum.y += v.y; csum.z += v.z; csum.w += v.w;
        csq.x += v.x * v.x; csq.y += v.y * v.y; csq.z += v.z * v.z; csq.w += v.w * v.w;
      }
    }
  }
  if (STATS) {
    atomicAdd(&stats[c0 + 0], csum.x);
    atomicAdd(&stats[c0 + 1], csum.y);
    atomicAdd(&stats[c0 + 2], csum.z);
    atomicAdd(&stats[c0 + 3], csum.w);
    atomicAdd(&stats[CC + c0 + 0], csq.x);
    atomicAdd(&stats[CC + c0 + 1], csq.y);
    atomicAdd(&stats[CC + c0 + 2], csq.z);
    atomicAdd(&stats[CC + c0 + 3], csq.w);
  }
}

// ---------------- BN finalize: a = g*rsqrt(var+eps), d = beta - mu*a ----------------
__global__ void finalize_kernel(const float* __restrict__ stats, const float* __restrict__ g,
                                const float* __restrict__ be, float* __restrict__ bn_a,
                                float* __restrict__ bn_d) {
  int c = threadIdx.x;
  float mu = stats[c] * (1.0f / NN);
  float var = stats[CC + c] * (1.0f / NN) - mu * mu;
  var = fmaxf(var, 0.f);
  float inv = rsqrtf(var + BN_EPS);
  float a = g[c] * inv;
  bn_a[c] = a;
  bn_d[c] = fmaf(-mu, a, be[c]);
}

// ---------------- BN2 + relu apply -> output slab ----------------
__global__ void apply_kernel(const float* __restrict__ tmp, const float* __restrict__ bn_a,
                             const float* __restrict__ bn_d, float* __restrict__ outslab) {
  int i = blockIdx.x * blockDim.x + threadIdx.x;  // indexes float4, SLAB/4 total
  float4 v = ((const float4*)tmp)[i];
  int c = (i & 31) << 2;
  float4 a = *(const float4*)&bn_a[c];
  float4 d = *(const float4*)&bn_d[c];
  v.x = fmaxf(fmaf(v.x, a.x, d.x), 0.f);
  v.y = fmaxf(fmaf(v.y, a.y, d.y), 0.f);
  v.z = fmaxf(fmaf(v.z, a.z, d.z), 0.f);
  v.w = fmaxf(fmaf(v.w, a.w, d.w), 0.f);
  ((float4*)outslab)[i] = v;
}

// ---------------- launch ----------------
extern "C" void kernel_launch(void* const* d_in, const int* in_sizes, int n_in,
                              void* d_out, int out_size, void* d_ws, size_t ws_size,
                              hipStream_t stream) {
  const float* x    = (const float*)d_in[0];
  const int*   edge = (const int*)d_in[1];
  // d_in[2] = batch: structurally node i -> graph i/1000 -> to_dense_batch == reshape
  const float* fh_W = (const float*)d_in[3];
  const float* fh_b = (const float*)d_in[4];
  const float* W1   = (const float*)d_in[5];
  const float* b1   = (const float*)d_in[6];
  const float* g1   = (const float*)d_in[7];
  const float* be1  = (const float*)d_in[8];
  const float* W2   = (const float*)d_in[9];
  const float* b2   = (const float*)d_in[10];
  const float* g2   = (const float*)d_in[11];
  const float* be2  = (const float*)d_in[12];
  float* out = (float*)d_out;

  const int* src = edge;
  const int* dst = edge + NE;

  // workspace layout (all 16B aligned)
  int* counts   = (int*)d_ws;        // 50048
  int* fill     = counts + 50048;    // 50048
  int* starts   = fill + 50048;      // 50048
  int* blocksum = starts + 50048;    // 256
  int* bucket   = blocksum + 256;    // 800000
  float* stats  = (float*)(bucket + NE);  // 512 (two BN stat sets)
  float* bn_a1  = stats + 512;
  float* bn_d1  = bn_a1 + CC;
  float* bn_a2  = bn_d1 + CC;
  float* bn_d2  = bn_a2 + CC;
  float* aggbuf = stats + 1024;      // SLAB floats
  float* tmp1   = aggbuf + SLAB;     // SLAB floats

  // CSR build (counts and fill are contiguous -> one zero pass)
  zero_int_kernel<<<(100096 + 255) / 256, 256, 0, stream>>>(counts, 100096);
  count_kernel<<<NE / 256, 256, 0, stream>>>(dst, counts);
  scan1_kernel<<<196, 256, 0, stream>>>(counts, starts, blocksum);
  scan2_kernel<<<1, 256, 0, stream>>>(blocksum, 196);
  scan3_kernel<<<196, 256, 0, stream>>>(starts, blocksum);
  fill_kernel<<<NE / 256, 256, 0, stream>>>(src, dst, starts, fill, bucket);

  // first head: out slab 0 = x @ fh_W + fh_b
  gemm_kernel<false, false><<<782, 256, 0, stream>>>(x, fh_W, fh_b, out, nullptr, nullptr, nullptr);

  for (int l = 0; l < 3; ++l) {
    const float* h = out + l * SLAB;
    zero_int_kernel<<<2, 256, 0, stream>>>((int*)stats, 512);
    gather_kernel<<<NN / 4, 256, 0, stream>>>(h, starts, counts, bucket, aggbuf);
    gemm_kernel<false, true><<<782, 256, 0, stream>>>(aggbuf, W1 + l * CC * CC, b1 + l * CC,
                                                      tmp1, nullptr, nullptr, stats);
    finalize_kernel<<<1, 128, 0, stream>>>(stats, g1 + l * CC, be1 + l * CC, bn_a1, bn_d1);
    gemm_kernel<true, true><<<782, 256, 0, stream>>>(tmp1, W2 + l * CC * CC, b2 + l * CC,
                                                     aggbuf, bn_a1, bn_d1, stats + 256);
    finalize_kernel<<<1, 128, 0, stream>>>(stats + 256, g2 + l * CC, be2 + l * CC, bn_a2, bn_d2);
    apply_kernel<<<SLAB / 4 / 256, 256, 0, stream>>>(aggbuf, bn_a2, bn_d2, out + (l + 1) * SLAB);
  }
}

// Round 3
// 823.492 us; speedup vs baseline: 9.4730x; 5.1143x over previous
//
#include <hip/hip_runtime.h>

#define NN 50000
#define NE 800000
#define CC 128
#define SLAB (NN * CC)
#define BN_EPS 1e-5f

typedef __attribute__((ext_vector_type(8))) short bf16x8;
typedef __attribute__((ext_vector_type(4))) float f32x4;

// ---------------- utility ----------------
__global__ void zero_int_kernel(int* __restrict__ p, int n) {
  int i = blockIdx.x * blockDim.x + threadIdx.x;
  if (i < n) p[i] = 0;
}

// ---------------- CSR build ----------------
__global__ void count_kernel(const int* __restrict__ dst, int* __restrict__ counts) {
  int e = blockIdx.x * blockDim.x + threadIdx.x;
  if (e < NE) atomicAdd(&counts[dst[e]], 1);
}

__global__ void scan1_kernel(const int* __restrict__ counts, int* __restrict__ excl,
                             int* __restrict__ blocksum) {
  __shared__ int s[256];
  int t = threadIdx.x;
  int i = blockIdx.x * 256 + t;
  int v = (i < NN) ? counts[i] : 0;
  s[t] = v;
  for (int off = 1; off < 256; off <<= 1) {
    __syncthreads();
    int add = (t >= off) ? s[t - off] : 0;
    __syncthreads();
    s[t] += add;
  }
  __syncthreads();
  if (i < NN) excl[i] = s[t] - v;
  if (t == 255) blocksum[blockIdx.x] = s[255];
}

__global__ void scan2_kernel(int* __restrict__ blocksum, int nb) {
  __shared__ int s[256];
  int t = threadIdx.x;
  int v = (t < nb) ? blocksum[t] : 0;
  s[t] = v;
  for (int off = 1; off < 256; off <<= 1) {
    __syncthreads();
    int add = (t >= off) ? s[t - off] : 0;
    __syncthreads();
    s[t] += add;
  }
  __syncthreads();
  if (t < nb) blocksum[t] = s[t] - v;
}

__global__ void scan3_kernel(int* __restrict__ excl, const int* __restrict__ blocksum) {
  int i = blockIdx.x * 256 + threadIdx.x;
  if (i < NN) excl[i] += blocksum[blockIdx.x];
}

__global__ void fill_kernel(const int* __restrict__ src, const int* __restrict__ dst,
                            const int* __restrict__ starts, int* __restrict__ fill,
                            int* __restrict__ bucket) {
  int e = blockIdx.x * blockDim.x + threadIdx.x;
  if (e < NE) {
    int d = dst[e];
    int pos = atomicAdd(&fill[d], 1);
    bucket[starts[d] + pos] = src[e];
  }
}

// ---------------- W prep: transpose + split to bf16 hi/lo, N-major ----------------
// matrices: 0 = fh_W, 1..3 = W1[l], 4..6 = W2[l]
__global__ void prep_w_kernel(const float* __restrict__ fh_W, const float* __restrict__ W1,
                              const float* __restrict__ W2, short* __restrict__ whi,
                              short* __restrict__ wlo) {
  int m = blockIdx.x;
  const float* src = (m == 0) ? fh_W : ((m <= 3) ? W1 + (m - 1) * CC * CC : W2 + (m - 4) * CC * CC);
  short* hi = whi + m * CC * CC;
  short* lo = wlo + m * CC * CC;
  for (int idx = threadIdx.x; idx < CC * CC; idx += 256) {
    int k = idx >> 7, n = idx & 127;
    float v = src[idx];
    unsigned u = __builtin_bit_cast(unsigned, v);
    unsigned short h = (unsigned short)(u >> 16);
    float hf = __builtin_bit_cast(float, ((unsigned)h) << 16);
    float r = v - hf;
    unsigned ur = __builtin_bit_cast(unsigned, r);
    hi[n * CC + k] = (short)h;
    lo[n * CC + k] = (short)(ur >> 16);
  }
}

// ---------------- gather: agg = h + sum_{j->i} h[j]; also zeroes stats ----------------
__global__ void gather_kernel(const float* __restrict__ h, const int* __restrict__ starts,
                              const int* __restrict__ counts, const int* __restrict__ bucket,
                              float* __restrict__ agg, float* __restrict__ stats) {
  if (blockIdx.x == 0 && threadIdx.x < 256) {
    stats[threadIdx.x] = 0.f;
    stats[256 + threadIdx.x] = 0.f;
  }
  int node = blockIdx.x * 4 + (threadIdx.x >> 6);
  int lane = threadIdx.x & 63;
  const float2* h2 = (const float2*)h;
  float2 acc = h2[node * 64 + lane];
  int s = starts[node];
  int n = counts[node];
  for (int i = 0; i < n; ++i) {
    int sr = bucket[s + i];
    float2 v = h2[sr * 64 + lane];
    acc.x += v.x;
    acc.y += v.y;
  }
  ((float2*)agg)[node * 64 + lane] = acc;
}

// ---------------- MFMA GEMM: out = op(A) @ W + bias ----------------
// op(A) = relu(bn_a[k]*A + bn_d[k]) when FUSE_BN. Split-bf16: a*w ~ ah*wh + al*wh + ah*wl.
// Block 256 = 4 waves; block tile 64 rows; wave tile 16 rows x 128 cols.
// Wt_hi/Wt_lo are N-major [n][k] bf16.
template <bool FUSE_BN, bool STATS>
__global__ __launch_bounds__(256) void gemm_mfma_kernel(
    const float* __restrict__ A, const short* __restrict__ Wt_hi, const short* __restrict__ Wt_lo,
    const float* __restrict__ bias, float* __restrict__ out,
    const float* __restrict__ bn_a, const float* __restrict__ bn_d, float* __restrict__ stats) {
  __shared__ float sred[2 * CC];
  const int t = threadIdx.x;
  const int wv = t >> 6;
  const int l = t & 63;
  const int m0 = blockIdx.x * 64 + wv * 16;
  const int row = m0 + (l & 15);        // A row this lane loads
  const int kg = (l >> 4) * 8;          // k-subchunk within 32

  if (STATS) {
    sred[t] = 0.f;
    sred[256 + t] = 0.f;  // wait: 2*CC = 256 total; guard below
  }
  // note: sred has 256 floats; the line above over-indexes if t>=0 -> fix: only t<256 exists,
  // sred[256+t] is OOB. Zero properly:
  // (we re-zero correctly here; compiler folds)
  __syncthreads();
  if (STATS) {
    if (t < 2 * CC) sred[t] = 0.f;
  }

  f32x4 acc[8];
#pragma unroll
  for (int i = 0; i < 8; ++i) acc[i] = (f32x4){0.f, 0.f, 0.f, 0.f};

#pragma unroll
  for (int ks = 0; ks < 4; ++ks) {
    // A fragment: 8 fp32 -> split bf16
    float av[8];
    if (row < NN) {
      const float* ap = &A[row * CC + ks * 32 + kg];
      float4 v0 = *(const float4*)ap;
      float4 v1 = *(const float4*)(ap + 4);
      av[0] = v0.x; av[1] = v0.y; av[2] = v0.z; av[3] = v0.w;
      av[4] = v1.x; av[5] = v1.y; av[6] = v1.z; av[7] = v1.w;
    } else {
#pragma unroll
      for (int i = 0; i < 8; ++i) av[i] = 0.f;
    }
    if (FUSE_BN) {
#pragma unroll
      for (int i = 0; i < 8; ++i) {
        int c = ks * 32 + kg + i;
        av[i] = fmaxf(fmaf(av[i], bn_a[c], bn_d[c]), 0.f);
      }
    }
    bf16x8 ah, al;
#pragma unroll
    for (int i = 0; i < 8; ++i) {
      unsigned u = __builtin_bit_cast(unsigned, av[i]);
      unsigned short hbits = (unsigned short)(u >> 16);
      float hf = __builtin_bit_cast(float, ((unsigned)hbits) << 16);
      float r = av[i] - hf;
      unsigned ur = __builtin_bit_cast(unsigned, r);
      ah[i] = (short)hbits;
      al[i] = (short)(ur >> 16);
    }
    const int wb = ks * 32 + kg;
#pragma unroll
    for (int nt = 0; nt < 8; ++nt) {
      int n = nt * 16 + (l & 15);
      bf16x8 wh = *(const bf16x8*)&Wt_hi[n * CC + wb];
      bf16x8 wl = *(const bf16x8*)&Wt_lo[n * CC + wb];
      acc[nt] = __builtin_amdgcn_mfma_f32_16x16x32_bf16(ah, wh, acc[nt], 0, 0, 0);
      acc[nt] = __builtin_amdgcn_mfma_f32_16x16x32_bf16(al, wh, acc[nt], 0, 0, 0);
      acc[nt] = __builtin_amdgcn_mfma_f32_16x16x32_bf16(ah, wl, acc[nt], 0, 0, 0);
    }
  }

  // epilogue: C layout col = lane&15, row = (lane>>4)*4 + reg
  if (STATS) __syncthreads();  // sred zeroed
  const int rbase = m0 + (l >> 4) * 4;
  const int cn = l & 15;
#pragma unroll
  for (int nt = 0; nt < 8; ++nt) {
    int c = nt * 16 + cn;
    float bv = bias[c];
    float s = 0.f, q = 0.f;
#pragma unroll
    for (int r = 0; r < 4; ++r) {
      int rr = rbase + r;
      if (rr < NN) {
        float v = acc[nt][r] + bv;
        out[rr * CC + c] = v;
        if (STATS) { s += v; q += v * v; }
      }
    }
    if (STATS) {
      s += __shfl_xor(s, 16); s += __shfl_xor(s, 32);
      q += __shfl_xor(q, 16); q += __shfl_xor(q, 32);
      if ((l >> 4) == 0) {
        atomicAdd(&sred[c], s);
        atomicAdd(&sred[CC + c], q);
      }
    }
  }
  if (STATS) {
    __syncthreads();
    if (t < 2 * CC) atomicAdd(&stats[t], sred[t]);
  }
}

// ---------------- BN finalize ----------------
__global__ void finalize_kernel(const float* __restrict__ stats, const float* __restrict__ g,
                                const float* __restrict__ be, float* __restrict__ bn_a,
                                float* __restrict__ bn_d) {
  int c = threadIdx.x;
  float mu = stats[c] * (1.0f / NN);
  float var = stats[CC + c] * (1.0f / NN) - mu * mu;
  var = fmaxf(var, 0.f);
  float inv = rsqrtf(var + BN_EPS);
  float a = g[c] * inv;
  bn_a[c] = a;
  bn_d[c] = fmaf(-mu, a, be[c]);
}

// ---------------- BN2 + relu apply -> output slab ----------------
__global__ void apply_kernel(const float* __restrict__ tmp, const float* __restrict__ bn_a,
                             const float* __restrict__ bn_d, float* __restrict__ outslab) {
  int i = blockIdx.x * blockDim.x + threadIdx.x;
  float4 v = ((const float4*)tmp)[i];
  int c = (i & 31) << 2;
  float4 a = *(const float4*)&bn_a[c];
  float4 d = *(const float4*)&bn_d[c];
  v.x = fmaxf(fmaf(v.x, a.x, d.x), 0.f);
  v.y = fmaxf(fmaf(v.y, a.y, d.y), 0.f);
  v.z = fmaxf(fmaf(v.z, a.z, d.z), 0.f);
  v.w = fmaxf(fmaf(v.w, a.w, d.w), 0.f);
  ((float4*)outslab)[i] = v;
}

// ---------------- launch ----------------
extern "C" void kernel_launch(void* const* d_in, const int* in_sizes, int n_in,
                              void* d_out, int out_size, void* d_ws, size_t ws_size,
                              hipStream_t stream) {
  const float* x    = (const float*)d_in[0];
  const int*   edge = (const int*)d_in[1];
  const float* fh_W = (const float*)d_in[3];
  const float* fh_b = (const float*)d_in[4];
  const float* W1   = (const float*)d_in[5];
  const float* b1   = (const float*)d_in[6];
  const float* g1   = (const float*)d_in[7];
  const float* be1  = (const float*)d_in[8];
  const float* W2   = (const float*)d_in[9];
  const float* b2   = (const float*)d_in[10];
  const float* g2   = (const float*)d_in[11];
  const float* be2  = (const float*)d_in[12];
  float* out = (float*)d_out;

  const int* src = edge;
  const int* dst = edge + NE;

  // workspace layout (16B aligned blocks)
  int* counts   = (int*)d_ws;            // 50048
  int* fill     = counts + 50048;        // 50048
  int* starts   = fill + 50048;          // 50048
  int* blocksum = starts + 50048;        // 256
  int* bucket   = blocksum + 256;        // 800000
  float* stats  = (float*)(bucket + NE); // 512
  float* bn_a1  = stats + 512;
  float* bn_d1  = bn_a1 + CC;
  float* bn_a2  = bn_d1 + CC;
  float* bn_d2  = bn_a2 + CC;
  short* whi    = (short*)(bn_d2 + CC);  // 7*16384 bf16 hi
  short* wlo    = whi + 7 * CC * CC;     // 7*16384 bf16 lo
  float* aggbuf = (float*)(wlo + 7 * CC * CC);  // SLAB floats
  float* tmp1   = aggbuf + SLAB;                // SLAB floats

  // CSR build
  zero_int_kernel<<<(100096 + 255) / 256, 256, 0, stream>>>(counts, 100096);
  count_kernel<<<NE / 256, 256, 0, stream>>>(dst, counts);
  scan1_kernel<<<196, 256, 0, stream>>>(counts, starts, blocksum);
  scan2_kernel<<<1, 256, 0, stream>>>(blocksum, 196);
  scan3_kernel<<<196, 256, 0, stream>>>(starts, blocksum);
  fill_kernel<<<NE / 256, 256, 0, stream>>>(src, dst, starts, fill, bucket);

  // weight prep (7 matrices -> N-major bf16 hi/lo)
  prep_w_kernel<<<7, 256, 0, stream>>>(fh_W, W1, W2, whi, wlo);

  // first head: out slab 0 = x @ fh_W + fh_b
  gemm_mfma_kernel<false, false><<<782, 256, 0, stream>>>(
      x, whi, wlo, fh_b, out, nullptr, nullptr, nullptr);

  for (int ly = 0; ly < 3; ++ly) {
    const float* h = out + ly * SLAB;
    gather_kernel<<<NN / 4, 256, 0, stream>>>(h, starts, counts, bucket, aggbuf, stats);
    gemm_mfma_kernel<false, true><<<782, 256, 0, stream>>>(
        aggbuf, whi + (1 + ly) * CC * CC, wlo + (1 + ly) * CC * CC, b1 + ly * CC,
        tmp1, nullptr, nullptr, stats);
    finalize_kernel<<<1, 128, 0, stream>>>(stats, g1 + ly * CC, be1 + ly * CC, bn_a1, bn_d1);
    gemm_mfma_kernel<true, true><<<782, 256, 0, stream>>>(
        tmp1, whi + (4 + ly) * CC * CC, wlo + (4 + ly) * CC * CC, b2 + ly * CC,
        aggbuf, bn_a1, bn_d1, stats + 256);
    finalize_kernel<<<1, 128, 0, stream>>>(stats + 256, g2 + ly * CC, be2 + ly * CC, bn_a2, bn_d2);
    apply_kernel<<<SLAB / 4 / 256, 256, 0, stream>>>(aggbuf, bn_a2, bn_d2, out + (ly + 1) * SLAB);
  }
}

// Round 4
// 811.442 us; speedup vs baseline: 9.6136x; 1.0148x over previous
//
#include <hip/hip_runtime.h>

#define NN 50000
#define NE 800000
#define CC 128
#define SLAB (NN * CC)
#define BN_EPS 1e-5f

typedef __attribute__((ext_vector_type(8))) short bf16x8;
typedef __attribute__((ext_vector_type(4))) float f32x4;
typedef unsigned short ushort_t;

__device__ inline ushort_t f2bf(float v) {
  unsigned u = __builtin_bit_cast(unsigned, v);
  unsigned r = u + 0x7FFFu + ((u >> 16) & 1u);
  return (ushort_t)(r >> 16);
}

// ---------------- utility ----------------
__global__ void zero_int_kernel(int* __restrict__ p, int n) {
  int i = blockIdx.x * blockDim.x + threadIdx.x;
  if (i < n) p[i] = 0;
}

// ---------------- CSR build ----------------
__global__ void count_kernel(const int* __restrict__ dst, int* __restrict__ counts) {
  int e = blockIdx.x * blockDim.x + threadIdx.x;
  if (e < NE) atomicAdd(&counts[dst[e]], 1);
}

__global__ void scan1_kernel(const int* __restrict__ counts, int* __restrict__ excl,
                             int* __restrict__ blocksum) {
  __shared__ int s[256];
  int t = threadIdx.x;
  int i = blockIdx.x * 256 + t;
  int v = (i < NN) ? counts[i] : 0;
  s[t] = v;
  for (int off = 1; off < 256; off <<= 1) {
    __syncthreads();
    int add = (t >= off) ? s[t - off] : 0;
    __syncthreads();
    s[t] += add;
  }
  __syncthreads();
  if (i < NN) excl[i] = s[t] - v;
  if (t == 255) blocksum[blockIdx.x] = s[255];
}

__global__ void scan2_kernel(int* __restrict__ blocksum, int nb) {
  __shared__ int s[256];
  int t = threadIdx.x;
  int v = (t < nb) ? blocksum[t] : 0;
  s[t] = v;
  for (int off = 1; off < 256; off <<= 1) {
    __syncthreads();
    int add = (t >= off) ? s[t - off] : 0;
    __syncthreads();
    s[t] += add;
  }
  __syncthreads();
  if (t < nb) blocksum[t] = s[t] - v;
}

__global__ void scan3_kernel(int* __restrict__ excl, const int* __restrict__ blocksum) {
  int i = blockIdx.x * 256 + threadIdx.x;
  if (i < NN) excl[i] += blocksum[blockIdx.x];
}

__global__ void fill_kernel(const int* __restrict__ src, const int* __restrict__ dst,
                            const int* __restrict__ starts, int* __restrict__ fill,
                            int* __restrict__ bucket) {
  int e = blockIdx.x * blockDim.x + threadIdx.x;
  if (e < NE) {
    int d = dst[e];
    int pos = atomicAdd(&fill[d], 1);
    bucket[starts[d] + pos] = src[e];
  }
}

// ---------------- W prep: transpose + split to bf16 hi/lo, N-major ----------------
__global__ void prep_w_kernel(const float* __restrict__ fh_W, const float* __restrict__ W1,
                              const float* __restrict__ W2, short* __restrict__ whi,
                              short* __restrict__ wlo) {
  int m = blockIdx.x;
  const float* src = (m == 0) ? fh_W : ((m <= 3) ? W1 + (m - 1) * CC * CC : W2 + (m - 4) * CC * CC);
  short* hi = whi + m * CC * CC;
  short* lo = wlo + m * CC * CC;
  for (int idx = threadIdx.x; idx < CC * CC; idx += 256) {
    int k = idx >> 7, n = idx & 127;
    float v = src[idx];
    unsigned u = __builtin_bit_cast(unsigned, v);
    unsigned short h = (unsigned short)(u >> 16);
    float hf = __builtin_bit_cast(float, ((unsigned)h) << 16);
    float r = v - hf;
    unsigned ur = __builtin_bit_cast(unsigned, r);
    hi[n * CC + k] = (short)h;
    lo[n * CC + k] = (short)(ur >> 16);
  }
}

// ---------------- gather (bf16 table): agg = h + sum_{j->i} h[j]; zeroes stats ----------------
__global__ void gather_kernel(const ushort_t* __restrict__ h16, const int* __restrict__ starts,
                              const int* __restrict__ counts, const int* __restrict__ bucket,
                              float* __restrict__ agg, float* __restrict__ stats) {
  if (blockIdx.x == 0) {
    stats[threadIdx.x] = 0.f;
    stats[256 + threadIdx.x] = 0.f;
  }
  int node = blockIdx.x * 4 + (threadIdx.x >> 6);
  int lane = threadIdx.x & 63;
  const unsigned* h2 = (const unsigned*)h16;  // 2 bf16 per uint, 64 uints per row
  unsigned u = h2[node * 64 + lane];
  float2 acc;
  acc.x = __builtin_bit_cast(float, u << 16);
  acc.y = __builtin_bit_cast(float, u & 0xFFFF0000u);
  int s = starts[node];
  int n = counts[node];
  for (int i = 0; i < n; ++i) {
    int sr = bucket[s + i];
    unsigned v = h2[sr * 64 + lane];
    acc.x += __builtin_bit_cast(float, v << 16);
    acc.y += __builtin_bit_cast(float, v & 0xFFFF0000u);
  }
  ((float2*)agg)[node * 64 + lane] = acc;
}

// ---------------- MFMA GEMM: out = op(A) @ W + bias ----------------
// op(A) = relu(bn_a[k]*A + bn_d[k]) when FUSE_BN. Split-bf16: a*w ~ ah*wh + al*wh + ah*wl.
// Block 256 = 4 waves; block tile 64 rows; wave tile 16 rows x 128 cols.
// May run in-place (out == A): block b reads only rows [b*64,b*64+64) and writes them
// only in the epilogue, after all reads.
template <bool FUSE_BN, bool STATS, bool W16>
__global__ __launch_bounds__(256) void gemm_mfma_kernel(
    const float* A, const short* __restrict__ Wt_hi, const short* __restrict__ Wt_lo,
    const float* __restrict__ bias, float* out, ushort_t* __restrict__ h16,
    const float* __restrict__ bn_a, const float* __restrict__ bn_d, float* __restrict__ stats) {
  __shared__ float sred[2 * CC];
  const int t = threadIdx.x;
  const int wv = t >> 6;
  const int l = t & 63;
  const int m0 = blockIdx.x * 64 + wv * 16;
  const int row = m0 + (l & 15);        // A row this lane loads
  const int kg = (l >> 4) * 8;          // k-subchunk within 32

  if (STATS) sred[t] = 0.f;

  f32x4 acc[8];
#pragma unroll
  for (int i = 0; i < 8; ++i) acc[i] = (f32x4){0.f, 0.f, 0.f, 0.f};

#pragma unroll
  for (int ks = 0; ks < 4; ++ks) {
    float av[8];
    if (row < NN) {
      const float* ap = &A[row * CC + ks * 32 + kg];
      float4 v0 = *(const float4*)ap;
      float4 v1 = *(const float4*)(ap + 4);
      av[0] = v0.x; av[1] = v0.y; av[2] = v0.z; av[3] = v0.w;
      av[4] = v1.x; av[5] = v1.y; av[6] = v1.z; av[7] = v1.w;
    } else {
#pragma unroll
      for (int i = 0; i < 8; ++i) av[i] = 0.f;
    }
    if (FUSE_BN) {
#pragma unroll
      for (int i = 0; i < 8; ++i) {
        int c = ks * 32 + kg + i;
        av[i] = fmaxf(fmaf(av[i], bn_a[c], bn_d[c]), 0.f);
      }
    }
    bf16x8 ah, al;
#pragma unroll
    for (int i = 0; i < 8; ++i) {
      unsigned u = __builtin_bit_cast(unsigned, av[i]);
      unsigned short hbits = (unsigned short)(u >> 16);
      float hf = __builtin_bit_cast(float, ((unsigned)hbits) << 16);
      float r = av[i] - hf;
      unsigned ur = __builtin_bit_cast(unsigned, r);
      ah[i] = (short)hbits;
      al[i] = (short)(ur >> 16);
    }
    const int wb = ks * 32 + kg;
#pragma unroll
    for (int nt = 0; nt < 8; ++nt) {
      int n = nt * 16 + (l & 15);
      bf16x8 wh = *(const bf16x8*)&Wt_hi[n * CC + wb];
      bf16x8 wl = *(const bf16x8*)&Wt_lo[n * CC + wb];
      acc[nt] = __builtin_amdgcn_mfma_f32_16x16x32_bf16(ah, wh, acc[nt], 0, 0, 0);
      acc[nt] = __builtin_amdgcn_mfma_f32_16x16x32_bf16(al, wh, acc[nt], 0, 0, 0);
      acc[nt] = __builtin_amdgcn_mfma_f32_16x16x32_bf16(ah, wl, acc[nt], 0, 0, 0);
    }
  }

  // epilogue: C layout col = lane&15, row = (lane>>4)*4 + reg
  if (STATS) __syncthreads();  // sred zeroed by all threads
  const int rbase = m0 + (l >> 4) * 4;
  const int cn = l & 15;
#pragma unroll
  for (int nt = 0; nt < 8; ++nt) {
    int c = nt * 16 + cn;
    float bv = bias[c];
    float s = 0.f, q = 0.f;
#pragma unroll
    for (int r = 0; r < 4; ++r) {
      int rr = rbase + r;
      if (rr < NN) {
        float v = acc[nt][r] + bv;
        out[rr * CC + c] = v;
        if (W16) h16[rr * CC + c] = f2bf(v);
        if (STATS) { s += v; q += v * v; }
      }
    }
    if (STATS) {
      s += __shfl_xor(s, 16); s += __shfl_xor(s, 32);
      q += __shfl_xor(q, 16); q += __shfl_xor(q, 32);
      if ((l >> 4) == 0) {
        atomicAdd(&sred[c], s);
        atomicAdd(&sred[CC + c], q);
      }
    }
  }
  if (STATS) {
    __syncthreads();
    atomicAdd(&stats[t], sred[t]);
  }
}

// ---------------- BN finalize ----------------
__global__ void finalize_kernel(const float* __restrict__ stats, const float* __restrict__ g,
                                const float* __restrict__ be, float* __restrict__ bn_a,
                                float* __restrict__ bn_d) {
  int c = threadIdx.x;
  float mu = stats[c] * (1.0f / NN);
  float var = stats[CC + c] * (1.0f / NN) - mu * mu;
  var = fmaxf(var, 0.f);
  float inv = rsqrtf(var + BN_EPS);
  float a = g[c] * inv;
  bn_a[c] = a;
  bn_d[c] = fmaf(-mu, a, be[c]);
}

// ---------------- BN2 + relu apply -> output slab (+ optional bf16 table) ----------------
__global__ void apply_kernel(const float* __restrict__ tmp, const float* __restrict__ bn_a,
                             const float* __restrict__ bn_d, float* __restrict__ outslab,
                             ushort_t* __restrict__ h16) {
  int i = blockIdx.x * blockDim.x + threadIdx.x;  // float4 index
  float4 v = ((const float4*)tmp)[i];
  int c = (i & 31) << 2;
  float4 a = *(const float4*)&bn_a[c];
  float4 d = *(const float4*)&bn_d[c];
  v.x = fmaxf(fmaf(v.x, a.x, d.x), 0.f);
  v.y = fmaxf(fmaf(v.y, a.y, d.y), 0.f);
  v.z = fmaxf(fmaf(v.z, a.z, d.z), 0.f);
  v.w = fmaxf(fmaf(v.w, a.w, d.w), 0.f);
  ((float4*)outslab)[i] = v;
  if (h16) {
    ushort_t p[4] = {f2bf(v.x), f2bf(v.y), f2bf(v.z), f2bf(v.w)};
    *(uint2*)&h16[i * 4] = *(uint2*)p;
  }
}

// ---------------- launch ----------------
extern "C" void kernel_launch(void* const* d_in, const int* in_sizes, int n_in,
                              void* d_out, int out_size, void* d_ws, size_t ws_size,
                              hipStream_t stream) {
  const float* x    = (const float*)d_in[0];
  const int*   edge = (const int*)d_in[1];
  const float* fh_W = (const float*)d_in[3];
  const float* fh_b = (const float*)d_in[4];
  const float* W1   = (const float*)d_in[5];
  const float* b1   = (const float*)d_in[6];
  const float* g1   = (const float*)d_in[7];
  const float* be1  = (const float*)d_in[8];
  const float* W2   = (const float*)d_in[9];
  const float* b2   = (const float*)d_in[10];
  const float* g2   = (const float*)d_in[11];
  const float* be2  = (const float*)d_in[12];
  float* out = (float*)d_out;

  const int* src = edge;
  const int* dst = edge + NE;

  // workspace layout
  int* counts   = (int*)d_ws;            // 50048
  int* fill     = counts + 50048;        // 50048
  int* starts   = fill + 50048;          // 50048
  int* blocksum = starts + 50048;        // 256
  int* bucket   = blocksum + 256;        // 800000
  float* stats  = (float*)(bucket + NE); // 512
  float* bn_a1  = stats + 512;
  float* bn_d1  = bn_a1 + CC;
  float* bn_a2  = bn_d1 + CC;
  float* bn_d2  = bn_a2 + CC;
  short* whi    = (short*)(bn_d2 + CC);  // 7*16384
  short* wlo    = whi + 7 * CC * CC;     // 7*16384
  ushort_t* h16 = (ushort_t*)(wlo + 7 * CC * CC);  // SLAB bf16 (12.8 MB)
  float* aggbuf = (float*)(h16 + SLAB);            // SLAB floats (25.6 MB)

  // CSR build
  zero_int_kernel<<<(100096 + 255) / 256, 256, 0, stream>>>(counts, 100096);
  count_kernel<<<NE / 256, 256, 0, stream>>>(dst, counts);
  scan1_kernel<<<196, 256, 0, stream>>>(counts, starts, blocksum);
  scan2_kernel<<<1, 256, 0, stream>>>(blocksum, 196);
  scan3_kernel<<<196, 256, 0, stream>>>(starts, blocksum);
  fill_kernel<<<NE / 256, 256, 0, stream>>>(src, dst, starts, fill, bucket);

  // weight prep
  prep_w_kernel<<<7, 256, 0, stream>>>(fh_W, W1, W2, whi, wlo);

  // first head: out slab 0 = x @ fh_W + fh_b, also writes bf16 table
  gemm_mfma_kernel<false, false, true><<<782, 256, 0, stream>>>(
      x, whi, wlo, fh_b, out, h16, nullptr, nullptr, nullptr);

  for (int ly = 0; ly < 3; ++ly) {
    gather_kernel<<<NN / 4, 256, 0, stream>>>(h16, starts, counts, bucket, aggbuf, stats);
    gemm_mfma_kernel<false, true, false><<<782, 256, 0, stream>>>(
        aggbuf, whi + (1 + ly) * CC * CC, wlo + (1 + ly) * CC * CC, b1 + ly * CC,
        aggbuf, nullptr, nullptr, nullptr, stats);
    finalize_kernel<<<1, 128, 0, stream>>>(stats, g1 + ly * CC, be1 + ly * CC, bn_a1, bn_d1);
    gemm_mfma_kernel<true, true, false><<<782, 256, 0, stream>>>(
        aggbuf, whi + (4 + ly) * CC * CC, wlo + (4 + ly) * CC * CC, b2 + ly * CC,
        aggbuf, nullptr, bn_a1, bn_d1, stats + 256);
    finalize_kernel<<<1, 128, 0, stream>>>(stats + 256, g2 + ly * CC, be2 + ly * CC, bn_a2, bn_d2);
    apply_kernel<<<SLAB / 4 / 256, 256, 0, stream>>>(
        aggbuf, bn_a2, bn_d2, out + (ly + 1) * SLAB, (ly < 2) ? h16 : (ushort_t*)nullptr);
  }
}

// Round 5
// 490.050 us; speedup vs baseline: 15.9186x; 1.6558x over previous
//
#include <hip/hip_runtime.h>

#define NN 50000
#define NE 800000
#define CC 128
#define SLAB (NN * CC)
#define BN_EPS 1e-5f

typedef __attribute__((ext_vector_type(8))) short bf16x8;
typedef __attribute__((ext_vector_type(4))) float f32x4;
typedef unsigned short ushort_t;

__device__ inline ushort_t f2bf(float v) {
  unsigned u = __builtin_bit_cast(unsigned, v);
  unsigned r = u + 0x7FFFu + ((u >> 16) & 1u);
  return (ushort_t)(r >> 16);
}

// ---------------- utility ----------------
__global__ void zero_int_kernel(int* __restrict__ p, int n) {
  int i = blockIdx.x * blockDim.x + threadIdx.x;
  if (i < n) p[i] = 0;
}

// ---------------- CSR build ----------------
__global__ void count_kernel(const int* __restrict__ dst, int* __restrict__ counts) {
  int e = blockIdx.x * blockDim.x + threadIdx.x;
  if (e < NE) atomicAdd(&counts[dst[e]], 1);
}

__global__ void scan1_kernel(const int* __restrict__ counts, int* __restrict__ excl,
                             int* __restrict__ blocksum) {
  __shared__ int s[256];
  int t = threadIdx.x;
  int i = blockIdx.x * 256 + t;
  int v = (i < NN) ? counts[i] : 0;
  s[t] = v;
  for (int off = 1; off < 256; off <<= 1) {
    __syncthreads();
    int add = (t >= off) ? s[t - off] : 0;
    __syncthreads();
    s[t] += add;
  }
  __syncthreads();
  if (i < NN) excl[i] = s[t] - v;
  if (t == 255) blocksum[blockIdx.x] = s[255];
}

__global__ void scan2_kernel(int* __restrict__ blocksum, int nb) {
  __shared__ int s[256];
  int t = threadIdx.x;
  int v = (t < nb) ? blocksum[t] : 0;
  s[t] = v;
  for (int off = 1; off < 256; off <<= 1) {
    __syncthreads();
    int add = (t >= off) ? s[t - off] : 0;
    __syncthreads();
    s[t] += add;
  }
  __syncthreads();
  if (t < nb) blocksum[t] = s[t] - v;
}

__global__ void scan3_kernel(int* __restrict__ excl, const int* __restrict__ blocksum) {
  int i = blockIdx.x * 256 + threadIdx.x;
  if (i < NN) excl[i] += blocksum[blockIdx.x];
}

__global__ void fill_kernel(const int* __restrict__ src, const int* __restrict__ dst,
                            const int* __restrict__ starts, int* __restrict__ fill,
                            int* __restrict__ bucket) {
  int e = blockIdx.x * blockDim.x + threadIdx.x;
  if (e < NE) {
    int d = dst[e];
    int pos = atomicAdd(&fill[d], 1);
    bucket[starts[d] + pos] = src[e];
  }
}

// ---------------- W prep: split + pack into per-(ks,nt) 64-lane fragments ----------------
// Kernel reads Wp[(ks*8+nt)*512 + l*8 + j] == W[k][n], n = nt*16+(l&15), k = ks*32+(l>>4)*8+j
__global__ void prep_w_kernel(const float* __restrict__ fh_W, const float* __restrict__ W1,
                              const float* __restrict__ W2, short* __restrict__ whi,
                              short* __restrict__ wlo) {
  int m = blockIdx.x;
  const float* src = (m == 0) ? fh_W : ((m <= 3) ? W1 + (m - 1) * CC * CC : W2 + (m - 4) * CC * CC);
  short* hi = whi + m * CC * CC;
  short* lo = wlo + m * CC * CC;
  for (int it = 0; it < 64; ++it) {
    int idx = it * 256 + threadIdx.x;  // 0..16383
    int j = idx & 7;
    int l = (idx >> 3) & 63;
    int nt = (idx >> 9) & 7;
    int ks = idx >> 12;
    int n = nt * 16 + (l & 15);
    int k = ks * 32 + ((l >> 4) << 3) + j;
    float v = src[k * CC + n];
    unsigned u = __builtin_bit_cast(unsigned, v);
    unsigned short h = (unsigned short)(u >> 16);
    float hf = __builtin_bit_cast(float, ((unsigned)h) << 16);
    float r = v - hf;
    unsigned ur = __builtin_bit_cast(unsigned, r);
    hi[idx] = (short)h;
    lo[idx] = (short)(ur >> 16);
  }
}

// ---------------- gather: agg = h + sum_{j->i} h[j]; quarter-wave MLP ----------------
__global__ void gather_kernel(const ushort_t* __restrict__ h16, const int* __restrict__ starts,
                              const int* __restrict__ counts, const int* __restrict__ bucket,
                              float* __restrict__ agg, float* __restrict__ stats) {
  if (blockIdx.x == 0) {
    stats[threadIdx.x] = 0.f;
    stats[256 + threadIdx.x] = 0.f;
  }
  const int node = blockIdx.x * 4 + (threadIdx.x >> 6);
  const int l = threadIdx.x & 63;
  const int j16 = l & 15;   // uint4 index within 256B row
  const int q = l >> 4;     // quarter
  const uint4* tbl = (const uint4*)h16;

  float acc[8];
  if (q == 0) {
    uint4 u = tbl[node * 16 + j16];
    acc[0] = __builtin_bit_cast(float, u.x << 16);
    acc[1] = __builtin_bit_cast(float, u.x & 0xFFFF0000u);
    acc[2] = __builtin_bit_cast(float, u.y << 16);
    acc[3] = __builtin_bit_cast(float, u.y & 0xFFFF0000u);
    acc[4] = __builtin_bit_cast(float, u.z << 16);
    acc[5] = __builtin_bit_cast(float, u.z & 0xFFFF0000u);
    acc[6] = __builtin_bit_cast(float, u.w << 16);
    acc[7] = __builtin_bit_cast(float, u.w & 0xFFFF0000u);
  } else {
#pragma unroll
    for (int k = 0; k < 8; ++k) acc[k] = 0.f;
  }

  const int s = starts[node];
  const int n = counts[node];
  for (int base = 0; base < n; base += 64) {
    int nb = min(n - base, 64);
    int idx = (l < nb) ? bucket[s + base + l] : 0;
    int jj = 0;
    for (; jj + 8 <= nb; jj += 8) {
      int sr0 = __shfl(idx, jj + q);
      int sr1 = __shfl(idx, jj + 4 + q);
      uint4 a = tbl[sr0 * 16 + j16];
      uint4 b = tbl[sr1 * 16 + j16];
      acc[0] += __builtin_bit_cast(float, a.x << 16);
      acc[1] += __builtin_bit_cast(float, a.x & 0xFFFF0000u);
      acc[2] += __builtin_bit_cast(float, a.y << 16);
      acc[3] += __builtin_bit_cast(float, a.y & 0xFFFF0000u);
      acc[4] += __builtin_bit_cast(float, a.z << 16);
      acc[5] += __builtin_bit_cast(float, a.z & 0xFFFF0000u);
      acc[6] += __builtin_bit_cast(float, a.w << 16);
      acc[7] += __builtin_bit_cast(float, a.w & 0xFFFF0000u);
      acc[0] += __builtin_bit_cast(float, b.x << 16);
      acc[1] += __builtin_bit_cast(float, b.x & 0xFFFF0000u);
      acc[2] += __builtin_bit_cast(float, b.y << 16);
      acc[3] += __builtin_bit_cast(float, b.y & 0xFFFF0000u);
      acc[4] += __builtin_bit_cast(float, b.z << 16);
      acc[5] += __builtin_bit_cast(float, b.z & 0xFFFF0000u);
      acc[6] += __builtin_bit_cast(float, b.w << 16);
      acc[7] += __builtin_bit_cast(float, b.w & 0xFFFF0000u);
    }
    for (; jj < nb; jj += 4) {
      int i = jj + q;
      int sr = __shfl(idx, i);
      if (i < nb) {
        uint4 a = tbl[sr * 16 + j16];
        acc[0] += __builtin_bit_cast(float, a.x << 16);
        acc[1] += __builtin_bit_cast(float, a.x & 0xFFFF0000u);
        acc[2] += __builtin_bit_cast(float, a.y << 16);
        acc[3] += __builtin_bit_cast(float, a.y & 0xFFFF0000u);
        acc[4] += __builtin_bit_cast(float, a.z << 16);
        acc[5] += __builtin_bit_cast(float, a.z & 0xFFFF0000u);
        acc[6] += __builtin_bit_cast(float, a.w << 16);
        acc[7] += __builtin_bit_cast(float, a.w & 0xFFFF0000u);
      }
    }
  }
  // cross-quarter reduce (quarters hold different neighbors' partials, same channels)
#pragma unroll
  for (int k = 0; k < 8; ++k) {
    acc[k] += __shfl_xor(acc[k], 16);
    acc[k] += __shfl_xor(acc[k], 32);
  }
  if (q == 0) {
    float4 w0 = make_float4(acc[0], acc[1], acc[2], acc[3]);
    float4 w1 = make_float4(acc[4], acc[5], acc[6], acc[7]);
    *(float4*)&agg[node * CC + j16 * 8] = w0;
    *(float4*)&agg[node * CC + j16 * 8 + 4] = w1;
  }
}

// ---------------- MFMA GEMM: out = op(A) @ W + bias ----------------
// LDS-staged A (stride 132, conflict-free b128 reads), packed coalesced W fragments.
// Split-bf16: a*w ~ ah*wh + al*wh + ah*wl. In-place safe (block reads only rows it writes).
template <bool FUSE_BN, bool STATS, bool W16>
__global__ __launch_bounds__(256) void gemm_mfma_kernel(
    const float* A, const short* __restrict__ Wp_hi, const short* __restrict__ Wp_lo,
    const float* __restrict__ bias, float* out, ushort_t* __restrict__ h16,
    const float* __restrict__ bn_a, const float* __restrict__ bn_d, float* __restrict__ stats) {
  __shared__ float As[64 * 132];
  __shared__ float sred[2 * CC];
  const int t = threadIdx.x;
  const int l = t & 63;
  const int wv = t >> 6;
  const int m0 = blockIdx.x * 64 + wv * 16;
  const int rowbase = blockIdx.x * 64;
  if (STATS) sred[t] = 0.f;

  // stage A tile (64 x 128 fp32) into LDS, coalesced; fuse BN+relu
#pragma unroll
  for (int i = 0; i < 8; ++i) {
    int f = i * 256 + t;          // float4 id 0..2047
    int r = f >> 5;               // 0..63
    int c = (f & 31) * 4;         // 0..124
    int rg = rowbase + r;
    float4 v = make_float4(0.f, 0.f, 0.f, 0.f);
    if (rg < NN) v = *(const float4*)&A[rg * CC + c];
    if (FUSE_BN) {
      v.x = fmaxf(fmaf(v.x, bn_a[c + 0], bn_d[c + 0]), 0.f);
      v.y = fmaxf(fmaf(v.y, bn_a[c + 1], bn_d[c + 1]), 0.f);
      v.z = fmaxf(fmaf(v.z, bn_a[c + 2], bn_d[c + 2]), 0.f);
      v.w = fmaxf(fmaf(v.w, bn_a[c + 3], bn_d[c + 3]), 0.f);
    }
    *(float4*)&As[r * 132 + c] = v;
  }
  __syncthreads();

  f32x4 acc[8];
#pragma unroll
  for (int i = 0; i < 8; ++i) acc[i] = (f32x4){0.f, 0.f, 0.f, 0.f};

  const int arow = (wv * 16 + (l & 15)) * 132;
  const int kg = (l >> 4) * 8;

#pragma unroll
  for (int ks = 0; ks < 4; ++ks) {
    const float* ap = &As[arow + ks * 32 + kg];
    bf16x8 ah, al;
#pragma unroll
    for (int i = 0; i < 8; ++i) {
      float a = ap[i];
      unsigned u = __builtin_bit_cast(unsigned, a);
      unsigned short hbits = (unsigned short)(u >> 16);
      float hf = __builtin_bit_cast(float, ((unsigned)hbits) << 16);
      float r = a - hf;
      unsigned ur = __builtin_bit_cast(unsigned, r);
      ah[i] = (short)hbits;
      al[i] = (short)(ur >> 16);
    }
#pragma unroll
    for (int nt = 0; nt < 8; ++nt) {
      const int base = (ks * 8 + nt) * 512 + l * 8;
      bf16x8 wh = *(const bf16x8*)&Wp_hi[base];
      bf16x8 wl = *(const bf16x8*)&Wp_lo[base];
      acc[nt] = __builtin_amdgcn_mfma_f32_16x16x32_bf16(ah, wh, acc[nt], 0, 0, 0);
      acc[nt] = __builtin_amdgcn_mfma_f32_16x16x32_bf16(al, wh, acc[nt], 0, 0, 0);
      acc[nt] = __builtin_amdgcn_mfma_f32_16x16x32_bf16(ah, wl, acc[nt], 0, 0, 0);
    }
  }

  // epilogue: C layout col = lane&15, row = (lane>>4)*4 + reg
  const int rbase = m0 + (l >> 4) * 4;
  const int cn = l & 15;
#pragma unroll
  for (int nt = 0; nt < 8; ++nt) {
    int c = nt * 16 + cn;
    float bv = bias[c];
    float s = 0.f, qq = 0.f;
#pragma unroll
    for (int r = 0; r < 4; ++r) {
      int rr = rbase + r;
      if (rr < NN) {
        float v = acc[nt][r] + bv;
        out[rr * CC + c] = v;
        if (W16) h16[rr * CC + c] = f2bf(v);
        if (STATS) { s += v; qq += v * v; }
      }
    }
    if (STATS) {
      s += __shfl_xor(s, 16); s += __shfl_xor(s, 32);
      qq += __shfl_xor(qq, 16); qq += __shfl_xor(qq, 32);
      if ((l >> 4) == 0) {
        atomicAdd(&sred[c], s);
        atomicAdd(&sred[CC + c], qq);
      }
    }
  }
  if (STATS) {
    __syncthreads();
    atomicAdd(&stats[t], sred[t]);
  }
}

// ---------------- BN finalize ----------------
__global__ void finalize_kernel(const float* __restrict__ stats, const float* __restrict__ g,
                                const float* __restrict__ be, float* __restrict__ bn_a,
                                float* __restrict__ bn_d) {
  int c = threadIdx.x;
  float mu = stats[c] * (1.0f / NN);
  float var = stats[CC + c] * (1.0f / NN) - mu * mu;
  var = fmaxf(var, 0.f);
  float inv = rsqrtf(var + BN_EPS);
  float a = g[c] * inv;
  bn_a[c] = a;
  bn_d[c] = fmaf(-mu, a, be[c]);
}

// ---------------- BN2 + relu apply -> output slab (+ optional bf16 table) ----------------
__global__ void apply_kernel(const float* __restrict__ tmp, const float* __restrict__ bn_a,
                             const float* __restrict__ bn_d, float* __restrict__ outslab,
                             ushort_t* __restrict__ h16) {
  int i = blockIdx.x * blockDim.x + threadIdx.x;
  float4 v = ((const float4*)tmp)[i];
  int c = (i & 31) << 2;
  float4 a = *(const float4*)&bn_a[c];
  float4 d = *(const float4*)&bn_d[c];
  v.x = fmaxf(fmaf(v.x, a.x, d.x), 0.f);
  v.y = fmaxf(fmaf(v.y, a.y, d.y), 0.f);
  v.z = fmaxf(fmaf(v.z, a.z, d.z), 0.f);
  v.w = fmaxf(fmaf(v.w, a.w, d.w), 0.f);
  ((float4*)outslab)[i] = v;
  if (h16) {
    ushort_t p[4] = {f2bf(v.x), f2bf(v.y), f2bf(v.z), f2bf(v.w)};
    *(uint2*)&h16[i * 4] = *(uint2*)p;
  }
}

// ---------------- launch ----------------
extern "C" void kernel_launch(void* const* d_in, const int* in_sizes, int n_in,
                              void* d_out, int out_size, void* d_ws, size_t ws_size,
                              hipStream_t stream) {
  const float* x    = (const float*)d_in[0];
  const int*   edge = (const int*)d_in[1];
  const float* fh_W = (const float*)d_in[3];
  const float* fh_b = (const float*)d_in[4];
  const float* W1   = (const float*)d_in[5];
  const float* b1   = (const float*)d_in[6];
  const float* g1   = (const float*)d_in[7];
  const float* be1  = (const float*)d_in[8];
  const float* W2   = (const float*)d_in[9];
  const float* b2   = (const float*)d_in[10];
  const float* g2   = (const float*)d_in[11];
  const float* be2  = (const float*)d_in[12];
  float* out = (float*)d_out;

  const int* src = edge;
  const int* dst = edge + NE;

  // workspace layout
  int* counts   = (int*)d_ws;            // 50048
  int* fill     = counts + 50048;        // 50048
  int* starts   = fill + 50048;          // 50048
  int* blocksum = starts + 50048;        // 256
  int* bucket   = blocksum + 256;        // 800000
  float* stats  = (float*)(bucket + NE); // 512
  float* bn_a1  = stats + 512;
  float* bn_d1  = bn_a1 + CC;
  float* bn_a2  = bn_d1 + CC;
  float* bn_d2  = bn_a2 + CC;
  short* whi    = (short*)(bn_d2 + CC);  // 7*16384 packed hi
  short* wlo    = whi + 7 * CC * CC;     // 7*16384 packed lo
  ushort_t* h16 = (ushort_t*)(wlo + 7 * CC * CC);  // SLAB bf16
  float* aggbuf = (float*)(h16 + SLAB);            // SLAB fp32

  // CSR build
  zero_int_kernel<<<(100096 + 255) / 256, 256, 0, stream>>>(counts, 100096);
  count_kernel<<<NE / 256, 256, 0, stream>>>(dst, counts);
  scan1_kernel<<<196, 256, 0, stream>>>(counts, starts, blocksum);
  scan2_kernel<<<1, 256, 0, stream>>>(blocksum, 196);
  scan3_kernel<<<196, 256, 0, stream>>>(starts, blocksum);
  fill_kernel<<<NE / 256, 256, 0, stream>>>(src, dst, starts, fill, bucket);

  // weight prep (packed fragments)
  prep_w_kernel<<<7, 256, 0, stream>>>(fh_W, W1, W2, whi, wlo);

  // first head
  gemm_mfma_kernel<false, false, true><<<782, 256, 0, stream>>>(
      x, whi, wlo, fh_b, out, h16, nullptr, nullptr, nullptr);

  for (int ly = 0; ly < 3; ++ly) {
    gather_kernel<<<NN / 4, 256, 0, stream>>>(h16, starts, counts, bucket, aggbuf, stats);
    gemm_mfma_kernel<false, true, false><<<782, 256, 0, stream>>>(
        aggbuf, whi + (1 + ly) * CC * CC, wlo + (1 + ly) * CC * CC, b1 + ly * CC,
        aggbuf, nullptr, nullptr, nullptr, stats);
    finalize_kernel<<<1, 128, 0, stream>>>(stats, g1 + ly * CC, be1 + ly * CC, bn_a1, bn_d1);
    gemm_mfma_kernel<true, true, false><<<782, 256, 0, stream>>>(
        aggbuf, whi + (4 + ly) * CC * CC, wlo + (4 + ly) * CC * CC, b2 + ly * CC,
        aggbuf, nullptr, bn_a1, bn_d1, stats + 256);
    finalize_kernel<<<1, 128, 0, stream>>>(stats + 256, g2 + ly * CC, be2 + ly * CC, bn_a2, bn_d2);
    apply_kernel<<<SLAB / 4 / 256, 256, 0, stream>>>(
        aggbuf, bn_a2, bn_d2, out + (ly + 1) * SLAB, (ly < 2) ? h16 : (ushort_t*)nullptr);
  }
}

// Round 6
// 481.268 us; speedup vs baseline: 16.2091x; 1.0182x over previous
//
#include <hip/hip_runtime.h>

#define NN 50000
#define NE 800000
#define CC 128
#define SLAB (NN * CC)
#define BN_EPS 1e-5f

typedef __attribute__((ext_vector_type(8))) short bf16x8;
typedef __attribute__((ext_vector_type(4))) float f32x4;
typedef unsigned short ushort_t;

__device__ inline ushort_t f2bf(float v) {
  unsigned u = __builtin_bit_cast(unsigned, v);
  unsigned r = u + 0x7FFFu + ((u >> 16) & 1u);
  return (ushort_t)(r >> 16);
}

// ---------------- utility ----------------
__global__ void zero_int_kernel(int* __restrict__ p, int n) {
  int i = blockIdx.x * blockDim.x + threadIdx.x;
  if (i < n) p[i] = 0;
}

// ---------------- CSR build ----------------
__global__ void count_kernel(const int* __restrict__ dst, int* __restrict__ counts) {
  int e = blockIdx.x * blockDim.x + threadIdx.x;
  if (e < NE) atomicAdd(&counts[dst[e]], 1);
}

__global__ void scan1_kernel(const int* __restrict__ counts, int* __restrict__ excl,
                             int* __restrict__ blocksum) {
  __shared__ int s[256];
  int t = threadIdx.x;
  int i = blockIdx.x * 256 + t;
  int v = (i < NN) ? counts[i] : 0;
  s[t] = v;
  for (int off = 1; off < 256; off <<= 1) {
    __syncthreads();
    int add = (t >= off) ? s[t - off] : 0;
    __syncthreads();
    s[t] += add;
  }
  __syncthreads();
  if (i < NN) excl[i] = s[t] - v;
  if (t == 255) blocksum[blockIdx.x] = s[255];
}

__global__ void scan2_kernel(int* __restrict__ blocksum, int nb) {
  __shared__ int s[256];
  int t = threadIdx.x;
  int v = (t < nb) ? blocksum[t] : 0;
  s[t] = v;
  for (int off = 1; off < 256; off <<= 1) {
    __syncthreads();
    int add = (t >= off) ? s[t - off] : 0;
    __syncthreads();
    s[t] += add;
  }
  __syncthreads();
  if (t < nb) blocksum[t] = s[t] - v;
}

__global__ void scan3_kernel(int* __restrict__ excl, const int* __restrict__ blocksum) {
  int i = blockIdx.x * 256 + threadIdx.x;
  if (i < NN) excl[i] += blocksum[blockIdx.x];
}

__global__ void fill_kernel(const int* __restrict__ src, const int* __restrict__ dst,
                            const int* __restrict__ starts, int* __restrict__ fill,
                            int* __restrict__ bucket) {
  int e = blockIdx.x * blockDim.x + threadIdx.x;
  if (e < NE) {
    int d = dst[e];
    int pos = atomicAdd(&fill[d], 1);
    bucket[starts[d] + pos] = src[e];
  }
}

// ---------------- W prep: split + pack into per-(ks,nt) 64-lane fragments ----------------
// Wp[(ks*8+nt)*512 + l*8 + j] == W[k][n], n = nt*16+(l&15), k = ks*32+(l>>4)*8+j
__global__ void prep_w_kernel(const float* __restrict__ fh_W, const float* __restrict__ W1,
                              const float* __restrict__ W2, short* __restrict__ whi,
                              short* __restrict__ wlo) {
  int m = blockIdx.x;
  const float* src = (m == 0) ? fh_W : ((m <= 3) ? W1 + (m - 1) * CC * CC : W2 + (m - 4) * CC * CC);
  short* hi = whi + m * CC * CC;
  short* lo = wlo + m * CC * CC;
  for (int it = 0; it < 64; ++it) {
    int idx = it * 256 + threadIdx.x;  // 0..16383
    int j = idx & 7;
    int l = (idx >> 3) & 63;
    int nt = (idx >> 9) & 7;
    int ks = idx >> 12;
    int n = nt * 16 + (l & 15);
    int k = ks * 32 + ((l >> 4) << 3) + j;
    float v = src[k * CC + n];
    unsigned u = __builtin_bit_cast(unsigned, v);
    unsigned short h = (unsigned short)(u >> 16);
    float hf = __builtin_bit_cast(float, ((unsigned)h) << 16);
    float r = v - hf;
    unsigned ur = __builtin_bit_cast(unsigned, r);
    hi[idx] = (short)h;
    lo[idx] = (short)(ur >> 16);
  }
}

// ---------------- gather: agg16 = bf16(h + sum_{j->i} h[j]); zeroes stats ----------------
__global__ void gather_kernel(const ushort_t* __restrict__ h16, const int* __restrict__ starts,
                              const int* __restrict__ counts, const int* __restrict__ bucket,
                              ushort_t* __restrict__ agg16, float* __restrict__ stats) {
  if (blockIdx.x == 0) {
    stats[threadIdx.x] = 0.f;
    stats[256 + threadIdx.x] = 0.f;
  }
  const int node = blockIdx.x * 4 + (threadIdx.x >> 6);
  const int l = threadIdx.x & 63;
  const int j16 = l & 15;
  const int q = l >> 4;
  const uint4* tbl = (const uint4*)h16;

  float acc[8];
  if (q == 0) {
    uint4 u = tbl[node * 16 + j16];
    acc[0] = __builtin_bit_cast(float, u.x << 16);
    acc[1] = __builtin_bit_cast(float, u.x & 0xFFFF0000u);
    acc[2] = __builtin_bit_cast(float, u.y << 16);
    acc[3] = __builtin_bit_cast(float, u.y & 0xFFFF0000u);
    acc[4] = __builtin_bit_cast(float, u.z << 16);
    acc[5] = __builtin_bit_cast(float, u.z & 0xFFFF0000u);
    acc[6] = __builtin_bit_cast(float, u.w << 16);
    acc[7] = __builtin_bit_cast(float, u.w & 0xFFFF0000u);
  } else {
#pragma unroll
    for (int k = 0; k < 8; ++k) acc[k] = 0.f;
  }

  const int s = starts[node];
  const int n = counts[node];
  for (int base = 0; base < n; base += 64) {
    int nb = min(n - base, 64);
    int idx = (l < nb) ? bucket[s + base + l] : 0;
    int jj = 0;
    for (; jj + 8 <= nb; jj += 8) {
      int sr0 = __shfl(idx, jj + q);
      int sr1 = __shfl(idx, jj + 4 + q);
      uint4 a = tbl[sr0 * 16 + j16];
      uint4 b = tbl[sr1 * 16 + j16];
      acc[0] += __builtin_bit_cast(float, a.x << 16);
      acc[1] += __builtin_bit_cast(float, a.x & 0xFFFF0000u);
      acc[2] += __builtin_bit_cast(float, a.y << 16);
      acc[3] += __builtin_bit_cast(float, a.y & 0xFFFF0000u);
      acc[4] += __builtin_bit_cast(float, a.z << 16);
      acc[5] += __builtin_bit_cast(float, a.z & 0xFFFF0000u);
      acc[6] += __builtin_bit_cast(float, a.w << 16);
      acc[7] += __builtin_bit_cast(float, a.w & 0xFFFF0000u);
      acc[0] += __builtin_bit_cast(float, b.x << 16);
      acc[1] += __builtin_bit_cast(float, b.x & 0xFFFF0000u);
      acc[2] += __builtin_bit_cast(float, b.y << 16);
      acc[3] += __builtin_bit_cast(float, b.y & 0xFFFF0000u);
      acc[4] += __builtin_bit_cast(float, b.z << 16);
      acc[5] += __builtin_bit_cast(float, b.z & 0xFFFF0000u);
      acc[6] += __builtin_bit_cast(float, b.w << 16);
      acc[7] += __builtin_bit_cast(float, b.w & 0xFFFF0000u);
    }
    for (; jj < nb; jj += 4) {
      int i = jj + q;
      int sr = __shfl(idx, i);
      if (i < nb) {
        uint4 a = tbl[sr * 16 + j16];
        acc[0] += __builtin_bit_cast(float, a.x << 16);
        acc[1] += __builtin_bit_cast(float, a.x & 0xFFFF0000u);
        acc[2] += __builtin_bit_cast(float, a.y << 16);
        acc[3] += __builtin_bit_cast(float, a.y & 0xFFFF0000u);
        acc[4] += __builtin_bit_cast(float, a.z << 16);
        acc[5] += __builtin_bit_cast(float, a.z & 0xFFFF0000u);
        acc[6] += __builtin_bit_cast(float, a.w << 16);
        acc[7] += __builtin_bit_cast(float, a.w & 0xFFFF0000u);
      }
    }
  }
#pragma unroll
  for (int k = 0; k < 8; ++k) {
    acc[k] += __shfl_xor(acc[k], 16);
    acc[k] += __shfl_xor(acc[k], 32);
  }
  if (q == 0) {
    uint4 o;
    o.x = (unsigned)f2bf(acc[0]) | ((unsigned)f2bf(acc[1]) << 16);
    o.y = (unsigned)f2bf(acc[2]) | ((unsigned)f2bf(acc[3]) << 16);
    o.z = (unsigned)f2bf(acc[4]) | ((unsigned)f2bf(acc[5]) << 16);
    o.w = (unsigned)f2bf(acc[6]) | ((unsigned)f2bf(acc[7]) << 16);
    ((uint4*)agg16)[node * 16 + j16] = o;
  }
}

// ---------------- MFMA GEMM (no LDS): out = op(A) @ W + bias ----------------
// MODE 0: A fp32 (x), split 3-MFMA, writes out fp32 + h16, no stats.
// MODE 1: A bf16 (agg16), 2-MFMA (a*wh + a*wl), writes out fp32, stats.
// MODE 2: A fp32 + inline BN1(stats_in,g,be)+relu -> bf16-rne, 2-MFMA, in-place fp32, stats.
template <int MODE>
__global__ __launch_bounds__(256) void gemm_mfma_kernel(
    const void* Aop, const short* __restrict__ Wp_hi, const short* __restrict__ Wp_lo,
    const float* __restrict__ bias, float* out, ushort_t* __restrict__ h16,
    const float* __restrict__ stats_in, const float* __restrict__ g,
    const float* __restrict__ be, float* __restrict__ stats_out) {
  constexpr bool STATS = (MODE != 0);
  __shared__ float sred[2 * CC];
  const int t = threadIdx.x;
  const int l = t & 63;
  const int wv = t >> 6;
  const int m0 = blockIdx.x * 64 + wv * 16;
  const int row = m0 + (l & 15);
  const int kg = (l >> 4) * 8;
  if (STATS) sred[t] = 0.f;

  f32x4 acc[8];
#pragma unroll
  for (int i = 0; i < 8; ++i) acc[i] = (f32x4){0.f, 0.f, 0.f, 0.f};

#pragma unroll
  for (int ks = 0; ks < 4; ++ks) {
    bf16x8 ah, al;
    if (MODE == 1) {
      if (row < NN) {
        ah = *(const bf16x8*)&((const ushort_t*)Aop)[row * CC + ks * 32 + kg];
      } else {
#pragma unroll
        for (int i = 0; i < 8; ++i) ah[i] = 0;
      }
    } else {
      float av[8];
      if (row < NN) {
        const float* ap = &((const float*)Aop)[row * CC + ks * 32 + kg];
        float4 v0 = *(const float4*)ap;
        float4 v1 = *(const float4*)(ap + 4);
        av[0] = v0.x; av[1] = v0.y; av[2] = v0.z; av[3] = v0.w;
        av[4] = v1.x; av[5] = v1.y; av[6] = v1.z; av[7] = v1.w;
      } else {
#pragma unroll
        for (int i = 0; i < 8; ++i) av[i] = 0.f;
      }
      if (MODE == 2) {
        // inline BN1 finalize + apply + relu, then bf16-rne
#pragma unroll
        for (int i = 0; i < 8; ++i) {
          int c = ks * 32 + kg + i;
          float mu = stats_in[c] * (1.0f / NN);
          float var = stats_in[CC + c] * (1.0f / NN) - mu * mu;
          var = fmaxf(var, 0.f);
          float a = g[c] * rsqrtf(var + BN_EPS);
          float d = fmaf(-mu, a, be[c]);
          av[i] = fmaxf(fmaf(av[i], a, d), 0.f);
          ah[i] = (short)f2bf(av[i]);
        }
      } else {  // MODE 0: split
#pragma unroll
        for (int i = 0; i < 8; ++i) {
          unsigned u = __builtin_bit_cast(unsigned, av[i]);
          unsigned short hbits = (unsigned short)(u >> 16);
          float hf = __builtin_bit_cast(float, ((unsigned)hbits) << 16);
          float r = av[i] - hf;
          unsigned ur = __builtin_bit_cast(unsigned, r);
          ah[i] = (short)hbits;
          al[i] = (short)(ur >> 16);
        }
      }
    }
#pragma unroll
    for (int nt = 0; nt < 8; ++nt) {
      const int base = (ks * 8 + nt) * 512 + l * 8;
      bf16x8 wh = *(const bf16x8*)&Wp_hi[base];
      bf16x8 wl = *(const bf16x8*)&Wp_lo[base];
      if (MODE == 0) {
        acc[nt] = __builtin_amdgcn_mfma_f32_16x16x32_bf16(ah, wh, acc[nt], 0, 0, 0);
        acc[nt] = __builtin_amdgcn_mfma_f32_16x16x32_bf16(al, wh, acc[nt], 0, 0, 0);
        acc[nt] = __builtin_amdgcn_mfma_f32_16x16x32_bf16(ah, wl, acc[nt], 0, 0, 0);
      } else {
        acc[nt] = __builtin_amdgcn_mfma_f32_16x16x32_bf16(ah, wh, acc[nt], 0, 0, 0);
        acc[nt] = __builtin_amdgcn_mfma_f32_16x16x32_bf16(ah, wl, acc[nt], 0, 0, 0);
      }
    }
  }

  // epilogue: C layout col = lane&15, row = (lane>>4)*4 + reg
  if (STATS) __syncthreads();
  const int rbase = m0 + (l >> 4) * 4;
  const int cn = l & 15;
#pragma unroll
  for (int nt = 0; nt < 8; ++nt) {
    int c = nt * 16 + cn;
    float bv = bias[c];
    float s = 0.f, qq = 0.f;
#pragma unroll
    for (int r = 0; r < 4; ++r) {
      int rr = rbase + r;
      if (rr < NN) {
        float v = acc[nt][r] + bv;
        out[rr * CC + c] = v;
        if (MODE == 0) h16[rr * CC + c] = f2bf(v);
        if (STATS) { s += v; qq += v * v; }
      }
    }
    if (STATS) {
      s += __shfl_xor(s, 16); s += __shfl_xor(s, 32);
      qq += __shfl_xor(qq, 16); qq += __shfl_xor(qq, 32);
      if ((l >> 4) == 0) {
        atomicAdd(&sred[c], s);
        atomicAdd(&sred[CC + c], qq);
      }
    }
  }
  if (STATS) {
    __syncthreads();
    atomicAdd(&stats_out[t], sred[t]);
  }
}

// ---------------- BN2(inline finalize) + relu apply -> output slab (+ bf16 table) ----------------
__global__ void apply_kernel(const float* __restrict__ tmp, const float* __restrict__ stats2,
                             const float* __restrict__ g2, const float* __restrict__ be2,
                             float* __restrict__ outslab, ushort_t* __restrict__ h16) {
  int i = blockIdx.x * blockDim.x + threadIdx.x;  // float4 index
  float4 v = ((const float4*)tmp)[i];
  int c = (i & 31) << 2;
  float4 sm = *(const float4*)&stats2[c];
  float4 sq = *(const float4*)&stats2[CC + c];
  float4 gg = *(const float4*)&g2[c];
  float4 bb = *(const float4*)&be2[c];
  float4 a, d;
  {
    float mu = sm.x * (1.0f / NN), var = fmaxf(sq.x * (1.0f / NN) - mu * mu, 0.f);
    a.x = gg.x * rsqrtf(var + BN_EPS); d.x = fmaf(-mu, a.x, bb.x);
    mu = sm.y * (1.0f / NN); var = fmaxf(sq.y * (1.0f / NN) - mu * mu, 0.f);
    a.y = gg.y * rsqrtf(var + BN_EPS); d.y = fmaf(-mu, a.y, bb.y);
    mu = sm.z * (1.0f / NN); var = fmaxf(sq.z * (1.0f / NN) - mu * mu, 0.f);
    a.z = gg.z * rsqrtf(var + BN_EPS); d.z = fmaf(-mu, a.z, bb.z);
    mu = sm.w * (1.0f / NN); var = fmaxf(sq.w * (1.0f / NN) - mu * mu, 0.f);
    a.w = gg.w * rsqrtf(var + BN_EPS); d.w = fmaf(-mu, a.w, bb.w);
  }
  v.x = fmaxf(fmaf(v.x, a.x, d.x), 0.f);
  v.y = fmaxf(fmaf(v.y, a.y, d.y), 0.f);
  v.z = fmaxf(fmaf(v.z, a.z, d.z), 0.f);
  v.w = fmaxf(fmaf(v.w, a.w, d.w), 0.f);
  ((float4*)outslab)[i] = v;
  if (h16) {
    ushort_t p[4] = {f2bf(v.x), f2bf(v.y), f2bf(v.z), f2bf(v.w)};
    *(uint2*)&h16[i * 4] = *(uint2*)p;
  }
}

// ---------------- launch ----------------
extern "C" void kernel_launch(void* const* d_in, const int* in_sizes, int n_in,
                              void* d_out, int out_size, void* d_ws, size_t ws_size,
                              hipStream_t stream) {
  const float* x    = (const float*)d_in[0];
  const int*   edge = (const int*)d_in[1];
  const float* fh_W = (const float*)d_in[3];
  const float* fh_b = (const float*)d_in[4];
  const float* W1   = (const float*)d_in[5];
  const float* b1   = (const float*)d_in[6];
  const float* g1   = (const float*)d_in[7];
  const float* be1  = (const float*)d_in[8];
  const float* W2   = (const float*)d_in[9];
  const float* b2   = (const float*)d_in[10];
  const float* g2   = (const float*)d_in[11];
  const float* be2  = (const float*)d_in[12];
  float* out = (float*)d_out;

  const int* src = edge;
  const int* dst = edge + NE;

  // workspace layout (all 16B aligned)
  int* counts   = (int*)d_ws;            // 50048
  int* fill     = counts + 50048;        // 50048
  int* starts   = fill + 50048;          // 50048
  int* blocksum = starts + 50048;        // 256
  int* bucket   = blocksum + 256;        // 800000
  float* stats  = (float*)(bucket + NE); // 512
  short* whi    = (short*)(stats + 512); // 7*16384 packed hi
  short* wlo    = whi + 7 * CC * CC;     // 7*16384 packed lo
  ushort_t* h16 = (ushort_t*)(wlo + 7 * CC * CC);  // SLAB bf16
  ushort_t* agg16 = h16 + SLAB;                    // SLAB bf16
  float* tmp    = (float*)(agg16 + SLAB);          // SLAB fp32

  // CSR build
  zero_int_kernel<<<(100096 + 255) / 256, 256, 0, stream>>>(counts, 100096);
  count_kernel<<<NE / 256, 256, 0, stream>>>(dst, counts);
  scan1_kernel<<<196, 256, 0, stream>>>(counts, starts, blocksum);
  scan2_kernel<<<1, 256, 0, stream>>>(blocksum, 196);
  scan3_kernel<<<196, 256, 0, stream>>>(starts, blocksum);
  fill_kernel<<<NE / 256, 256, 0, stream>>>(src, dst, starts, fill, bucket);

  // weight prep (packed fragments)
  prep_w_kernel<<<7, 256, 0, stream>>>(fh_W, W1, W2, whi, wlo);

  // first head: out slab 0 = x @ fh_W + fh_b (+ h16 table)
  gemm_mfma_kernel<0><<<782, 256, 0, stream>>>(
      x, whi, wlo, fh_b, out, h16, nullptr, nullptr, nullptr, nullptr);

  for (int ly = 0; ly < 3; ++ly) {
    gather_kernel<<<NN / 4, 256, 0, stream>>>(h16, starts, counts, bucket, agg16, stats);
    gemm_mfma_kernel<1><<<782, 256, 0, stream>>>(
        agg16, whi + (1 + ly) * CC * CC, wlo + (1 + ly) * CC * CC, b1 + ly * CC,
        tmp, nullptr, nullptr, nullptr, nullptr, stats);
    gemm_mfma_kernel<2><<<782, 256, 0, stream>>>(
        tmp, whi + (4 + ly) * CC * CC, wlo + (4 + ly) * CC * CC, b2 + ly * CC,
        tmp, nullptr, stats, g1 + ly * CC, be1 + ly * CC, stats + 256);
    apply_kernel<<<SLAB / 4 / 256, 256, 0, stream>>>(
        tmp, stats + 256, g2 + ly * CC, be2 + ly * CC, out + (ly + 1) * SLAB,
        (ly < 2) ? h16 : (ushort_t*)nullptr);
  }
}